// Round 11
// baseline (327.542 us; speedup 1.0000x reference)
//
#include <hip/hip_runtime.h>
#include <hip/hip_bf16.h>
#include <cstdint>

constexpr int BATCH = 4;
constexpr int CDIM  = 512;
constexpr int NHEAD = 8;
constexpr int HD    = 64;
constexpr int FSP   = 56;
constexpr int NTOK  = FSP * FSP;  // 3136
constexpr int KH    = 28;
constexpr int KNTOK = KH * KH;    // 784
constexpr float SCALE_ATT = 0.125f;
constexpr int BIAS_LD = 832;      // 13 chunks * 64, tail baked to -3e4

typedef _Float16 f16;
typedef __attribute__((ext_vector_type(8))) _Float16 half8;
typedef __attribute__((ext_vector_type(4))) float  floatx4;

// ---------------------------------------------------------------------------
// Mega-prep: transposes + Wsr reorder + analytic bias table (coalesced).
// ---------------------------------------------------------------------------
__device__ __forceinline__ void tr64(const float* __restrict__ in,
                                     f16* __restrict__ out, int R, int C,
                                     int r0, int c0, float (*sm)[65], int tid) {
  const int rr = tid >> 2, cs = (tid & 3) * 16;
  const float* src = in + (size_t)(r0 + rr) * C + c0 + cs;
#pragma unroll
  for (int j = 0; j < 16; j += 4) *(float4*)&sm[rr][cs + j] = *(const float4*)&src[j];
  __syncthreads();
  f16* dh = out + (size_t)(c0 + rr) * R + r0 + cs;
  half8 v0, v1;
#pragma unroll
  for (int j = 0; j < 8; ++j) v0[j] = (f16)sm[cs + j][rr];
#pragma unroll
  for (int j = 0; j < 8; ++j) v1[j] = (f16)sm[cs + 8 + j][rr];
  *(half8*)&dh[0] = v0;
  *(half8*)&dh[8] = v1;
}

__global__ __launch_bounds__(256) void k_prep(const float* __restrict__ x,
                                              const float* __restrict__ Wq,
                                              const float* __restrict__ Wkv,
                                              const float* __restrict__ Wp,
                                              const float* __restrict__ Wsr,
                                              const float* __restrict__ pos,
                                              f16* __restrict__ xT,
                                              f16* __restrict__ WqT,
                                              f16* __restrict__ WkvT,
                                              f16* __restrict__ WpT,
                                              f16* __restrict__ WsrP,
                                              float* __restrict__ biasT) {
  __shared__ float sm[64][65];
  const int tid = threadIdx.x;
  int bid = blockIdx.x;
  if (bid < 1568) {
    const int b = bid / 392, r = bid % 392;
    tr64(x + (size_t)b * CDIM * NTOK, xT + (size_t)b * NTOK * CDIM,
         CDIM, NTOK, (r % 8) * 64, (r / 8) * 64, sm, tid);
    return;
  }
  bid -= 1568;
  if (bid < 64)  { tr64(Wq,  WqT,  512, 512,  (bid % 8) * 64, (bid / 8) * 64, sm, tid); return; }
  bid -= 64;
  if (bid < 128) { tr64(Wkv, WkvT, 512, 1024, (bid % 8) * 64, (bid / 8) * 64, sm, tid); return; }
  bid -= 128;
  if (bid < 64)  { tr64(Wp,  WpT,  512, 512,  (bid % 8) * 64, (bid / 8) * 64, sm, tid); return; }
  bid -= 64;
  if (bid < 512) {
    const float* src = Wsr + (size_t)bid * 2048;
    f16* dh = WsrP + (size_t)bid * 2048;
    for (int kp = tid; kp < 2048; kp += 256) {
      const int dd = kp >> 9, c = kp & 511;
      dh[kp] = (f16)src[c * 4 + dd];
    }
    return;
  }
  bid -= 512;
  {
    const int n = bid;
    const int in_ = n / FSP, jn = n % FSP;
    const int cbase = 55 * 111 + 55 - in_ * 111 - jn;
    float* dst = biasT + (size_t)n * BIAS_LD;
    for (int m = tid; m < BIAS_LD; m += 256) {   // coalesced pos reads
      float v = -30000.f;
      if (m < KNTOK) v = pos[cbase + (m / FSP) * 111 + (m % FSP)];
      const int jc = m >> 6, w = m & 63, t = w >> 4, txx = w & 15;
      dst[jc * 64 + txx * 4 + t] = v;
    }
  }
}

// ---------------------------------------------------------------------------
// m97-style MFMA GEMM core: 128x128 tile, BK=32, unpadded LDS [128][32],
// async global->LDS staging via global_load_lds width-16.
// ---------------------------------------------------------------------------
struct GemmSmem { f16 A[128 * 32]; f16 B[128 * 32]; };  // 8 KB + 8 KB

__device__ __forceinline__ void gl_lds(const f16* g, f16* l) {
  __builtin_amdgcn_global_load_lds(
      (const __attribute__((address_space(1))) void*)g,
      (__attribute__((address_space(3))) void*)l, 16, 0, 0);
}

__device__ __forceinline__ void gemm128(GemmSmem* sm,
    const f16* a0, const f16* a1, const f16* b0, const f16* b1,
    int lane, int wv, int wm, int wn, int quad, int tx,
    floatx4 acc[4][4]) {
  f16* lA0 = sm->A + wv * 1024 + lane * 8;
  f16* lA1 = sm->A + wv * 1024 + 512 + lane * 8;
  f16* lB0 = sm->B + wv * 1024 + lane * 8;
  f16* lB1 = sm->B + wv * 1024 + 512 + lane * 8;
  for (int it = 0; it < 16; ++it) {
    gl_lds(a0 + it * 32, lA0);
    gl_lds(a1 + it * 32, lA1);
    gl_lds(b0 + it * 32, lB0);
    gl_lds(b1 + it * 32, lB1);
    __syncthreads();
    half8 af[4], bf[4];
#pragma unroll
    for (int i = 0; i < 4; ++i)
      af[i] = *(const half8*)&sm->A[(wm * 64 + i * 16 + tx) * 32 + quad * 8];
#pragma unroll
    for (int j = 0; j < 4; ++j)
      bf[j] = *(const half8*)&sm->B[(wn * 64 + j * 16 + tx) * 32 + quad * 8];
#pragma unroll
    for (int j = 0; j < 4; ++j)
#pragma unroll
      for (int i = 0; i < 4; ++i)
        acc[i][j] = __builtin_amdgcn_mfma_f32_16x16x32_f16(af[i], bf[j], acc[i][j], 0, 0, 0);
    __syncthreads();
  }
}

#define GEMM128_PRE()                                                     \
  const int tid = threadIdx.x, lane = tid & 63, wv = tid >> 6;            \
  const int wm = wv & 1, wn = wv >> 1, quad = lane >> 4, tx = lane & 15;  \
  const int lr = lane >> 2, lc = (lane & 3) * 8;                          \
  floatx4 acc[4][4];                                                      \
  _Pragma("unroll") for (int i = 0; i < 4; ++i)                           \
  _Pragma("unroll") for (int j = 0; j < 4; ++j)                           \
      acc[i][j] = (floatx4){0.f, 0.f, 0.f, 0.f};

// ---------------------------------------------------------------------------
// GEMM-A: Q projection (400 blocks) + SR-conv split-K=2 (224 blocks).
// ---------------------------------------------------------------------------
__global__ __launch_bounds__(256) void k_gemmA(const f16* __restrict__ xT,
                                               const f16* __restrict__ WqT,
                                               f16* __restrict__ Qh,
                                               const f16* __restrict__ WsrP,
                                               float* __restrict__ XRp) {
  __shared__ GemmSmem sm;
  GEMM128_PRE();
  int bid = blockIdx.x;
  if (bid < 400) {            // ---- Q projection: b4 x m25 x n4 ----
    const int b = bid / 100, t = bid % 100;
    const int m0 = (t >> 2) * 128, n0 = (t & 3) * 128;
    const f16* xb = xT + (size_t)b * NTOK * CDIM;
    const int r0 = wv * 32 + lr, r1 = r0 + 16;
    const f16* a0 = xb + (size_t)min(m0 + r0, NTOK - 1) * CDIM + lc;
    const f16* a1 = xb + (size_t)min(m0 + r1, NTOK - 1) * CDIM + lc;
    const f16* b0 = WqT + (size_t)(n0 + r0) * CDIM + lc;
    const f16* b1 = WqT + (size_t)(n0 + r1) * CDIM + lc;
    gemm128(&sm, a0, a1, b0, b1, lane, wv, wm, wn, quad, tx, acc);
    f16* qhB = Qh + (size_t)b * NTOK * CDIM;
#pragma unroll
    for (int i = 0; i < 4; ++i)
#pragma unroll
      for (int rg = 0; rg < 4; ++rg) {
        const int m = m0 + wm * 64 + i * 16 + quad * 4 + rg;
        if (m >= NTOK) continue;
#pragma unroll
        for (int j = 0; j < 4; ++j)
          qhB[(size_t)m * CDIM + n0 + wn * 64 + j * 16 + tx] = (f16)acc[i][j][rg];
      }
  } else {                    // ---- SR conv split-K=2: (b,kc2)8 x m7 x n4 ----
    bid -= 400;
    const int bkc = bid / 28, r = bid % 28;
    const int b = bkc >> 1, kc2 = bkc & 1;
    const int m0 = (r >> 2) * 128, n0 = (r & 3) * 128;
    const f16* xb = xT + (size_t)b * NTOK * CDIM;
    const int r0 = wv * 32 + lr, r1 = r0 + 16;
    int am0 = m0 + r0; if (am0 >= KNTOK) am0 = 0;
    int am1 = m0 + r1; if (am1 >= KNTOK) am1 = 0;
    const int base0 = 112 * (am0 / KH) + 2 * (am0 % KH);
    const int base1 = 112 * (am1 / KH) + 2 * (am1 % KH);
#pragma unroll
    for (int dd2 = 0; dd2 < 2; ++dd2) {
      const int dd = kc2 * 2 + dd2;
      const int sp0 = base0 + (dd >> 1) * FSP + (dd & 1);
      const int sp1 = base1 + (dd >> 1) * FSP + (dd & 1);
      const f16* a0 = xb + (size_t)sp0 * CDIM + lc;
      const f16* a1 = xb + (size_t)sp1 * CDIM + lc;
      const f16* b0 = WsrP + (size_t)(n0 + r0) * 2048 + dd * 512 + lc;
      const f16* b1 = WsrP + (size_t)(n0 + r1) * 2048 + dd * 512 + lc;
      gemm128(&sm, a0, a1, b0, b1, lane, wv, wm, wn, quad, tx, acc);
    }
    float* dst = XRp + (size_t)(kc2 * BATCH + b) * KNTOK * CDIM;
#pragma unroll
    for (int i = 0; i < 4; ++i)
#pragma unroll
      for (int rg = 0; rg < 4; ++rg) {
        const int m = m0 + wm * 64 + i * 16 + quad * 4 + rg;
        if (m >= KNTOK) continue;
#pragma unroll
        for (int j = 0; j < 4; ++j)
          dst[(size_t)m * CDIM + n0 + wn * 64 + j * 16 + tx] = acc[i][j][rg];
      }
  }
}

// ---------------------------------------------------------------------------
// LN: sum 2 split-K partials + b_sr, LayerNorm, output fp16.
// ---------------------------------------------------------------------------
__global__ __launch_bounds__(256) void k_ln(const float* __restrict__ XRp,
                                            const float* __restrict__ b_sr,
                                            const float* __restrict__ gamma,
                                            const float* __restrict__ beta,
                                            f16* __restrict__ oh) {
  const int row = blockIdx.x;
  const size_t slab = (size_t)BATCH * KNTOK * CDIM;
  const float* p = XRp + (size_t)row * CDIM;
  const int tid = threadIdx.x;
  const float v0 = p[tid] + p[tid + slab] + b_sr[tid];
  const float v1 = p[tid + 256] + p[tid + 256 + slab] + b_sr[tid + 256];
  float s = v0 + v1;
  float s2 = v0 * v0 + v1 * v1;
#pragma unroll
  for (int mask = 32; mask >= 1; mask >>= 1) {
    s  += __shfl_xor(s, mask, 64);
    s2 += __shfl_xor(s2, mask, 64);
  }
  __shared__ float ws[4], ws2[4];
  const int wid = tid >> 6;
  if ((tid & 63) == 0) { ws[wid] = s; ws2[wid] = s2; }
  __syncthreads();
  const float ts  = ws[0] + ws[1] + ws[2] + ws[3];
  const float ts2 = ws2[0] + ws2[1] + ws2[2] + ws2[3];
  const float mu  = ts * (1.f / CDIM);
  const float var = ts2 * (1.f / CDIM) - mu * mu;
  const float rs  = rsqrtf(var + 1e-5f);
  const size_t base = (size_t)row * CDIM;
  oh[base + tid]       = (f16)((v0 - mu) * rs * gamma[tid] + beta[tid]);
  oh[base + tid + 256] = (f16)((v1 - mu) * rs * gamma[tid + 256] + beta[tid + 256]);
}

// ---------------------------------------------------------------------------
// KV projection (224 blocks) + scatter.  K -> [b][h][m][d]; V -> [b][h][d][m].
// ---------------------------------------------------------------------------
__global__ __launch_bounds__(256) void k_kvproj(const f16* __restrict__ XRh,
                                                const f16* __restrict__ WkvT,
                                                f16* __restrict__ Kh,
                                                f16* __restrict__ Vt) {
  __shared__ GemmSmem sm;
  GEMM128_PRE();
  const int bid = blockIdx.x;
  const int b = bid / 56, r = bid % 56;
  const int m0 = (r / 8) * 128, n0 = (r % 8) * 128;
  const f16* ab = XRh + (size_t)b * KNTOK * CDIM;
  const int r0 = wv * 32 + lr, r1 = r0 + 16;
  const f16* a0 = ab + (size_t)min(m0 + r0, KNTOK - 1) * CDIM + lc;
  const f16* a1 = ab + (size_t)min(m0 + r1, KNTOK - 1) * CDIM + lc;
  const f16* b0 = WkvT + (size_t)(n0 + r0) * CDIM + lc;
  const f16* b1 = WkvT + (size_t)(n0 + r1) * CDIM + lc;
  gemm128(&sm, a0, a1, b0, b1, lane, wv, wm, wn, quad, tx, acc);
#pragma unroll
  for (int i = 0; i < 4; ++i)
#pragma unroll
    for (int rg = 0; rg < 4; ++rg) {
      const int m = m0 + wm * 64 + i * 16 + quad * 4 + rg;
      if (m >= KNTOK) continue;
#pragma unroll
      for (int j = 0; j < 4; ++j) {
        const int o2 = n0 + wn * 64 + j * 16 + tx;
        const int d = o2 >> 4, hh = (o2 >> 1) & 7;
        const float v = acc[i][j][rg];
        if (o2 & 1)
          Vt[((size_t)(b * NHEAD + hh) * HD + d) * KNTOK + m] = (f16)v;
        else
          Kh[((size_t)(b * NHEAD + hh) * KNTOK + m) * HD + d] = (f16)v;
      }
    }
}

// ---------------------------------------------------------------------------
// Attention: 128-row Q tiles, Q held in REGISTERS (staged through the wave's
// own Ps strip, intra-wave, zero barriers -> no Qhs array; LDS 36.9 KB).
// LDS-staged K/V chunks with register prefetch; static-max softmax.
// Grid (32 = b*8+h fast, 25 q-tiles).
// ---------------------------------------------------------------------------
#define LSTR 72
__global__ __launch_bounds__(256) void k_attn(const f16* __restrict__ Qh,
                                              const f16* __restrict__ Kh,
                                              const f16* __restrict__ Vt,
                                              const float* __restrict__ biasT,
                                              f16* __restrict__ Oh) {
  __shared__ f16 Khs[64][LSTR], Vts[64][LSTR];
  __shared__ f16 Ps[4][32][LSTR];
  const int b = blockIdx.x >> 3, h = blockIdx.x & 7;
  const int n0 = blockIdx.y * 128;
  const int tid = threadIdx.x, lane = tid & 63, wv = tid >> 6;
  const int quad = lane >> 4, tx = lane & 15;
  const int rr = tid >> 2, sg = (tid & 3) * 16;   // K/V staging coords

  const f16* khB = Kh + (size_t)(b * NHEAD + h) * KNTOK * HD;
  const f16* vtB = Vt + (size_t)(b * NHEAD + h) * HD * KNTOK;
  f16* PsW = &Ps[wv][0][0];

  {  // stage chunk 0 of K/V (block-wide)
    const size_t koff = (size_t)rr * HD + sg;
    *(half8*)&Khs[rr][sg]     = *(const half8*)&khB[koff];
    *(half8*)&Khs[rr][sg + 8] = *(const half8*)&khB[koff + 8];
    const size_t voff = (size_t)rr * KNTOK + sg;
    *(half8*)&Vts[rr][sg]     = *(const half8*)&vtB[voff];
    *(half8*)&Vts[rr][sg + 8] = *(const half8*)&vtB[voff + 8];
  }

  // ---- load Q fragments into registers via the wave's own Ps strip ----
  half8 qreg[2][2];   // [i][ks]
  {
    const int qr2 = lane >> 1, qs2 = (lane & 1) * 32;
    const int qrow = min(n0 + wv * 32 + qr2, NTOK - 1);
    const f16* src = Qh + ((size_t)b * NTOK + qrow) * CDIM + h * HD + qs2;
    *(half8*)&PsW[qr2 * LSTR + qs2]      = *(const half8*)&src[0];
    *(half8*)&PsW[qr2 * LSTR + qs2 + 8]  = *(const half8*)&src[8];
    *(half8*)&PsW[qr2 * LSTR + qs2 + 16] = *(const half8*)&src[16];
    *(half8*)&PsW[qr2 * LSTR + qs2 + 24] = *(const half8*)&src[24];
#pragma unroll
    for (int i = 0; i < 2; ++i)
#pragma unroll
      for (int ks = 0; ks < 2; ++ks)
        qreg[i][ks] = *(const half8*)&PsW[(i * 16 + tx) * LSTR + ks * 32 + quad * 8];
  }

  size_t bbase[2][4];
#pragma unroll
  for (int i = 0; i < 2; ++i)
#pragma unroll
    for (int rg = 0; rg < 4; ++rg) {
      const int grow = min(n0 + wv * 32 + i * 16 + quad * 4 + rg, NTOK - 1);
      bbase[i][rg] = (size_t)grow * BIAS_LD + tx * 4;
    }

  floatx4 acc_o[2][4];
#pragma unroll
  for (int i = 0; i < 2; ++i)
#pragma unroll
    for (int t = 0; t < 4; ++t) acc_o[i][t] = (floatx4){0.f, 0.f, 0.f, 0.f};
  float l_part[2][4] = {};
  __syncthreads();

  half8 nk0, nk1, nv0, nv1;
  for (int jc = 0; jc < 13; ++jc) {
    if (jc < 12) {  // register prefetch of next K/V chunk
      const int mbn = (jc + 1) * 64;
      const int km = min(mbn + rr, KNTOK - 1);
      const size_t koff = (size_t)km * HD + sg;
      nk0 = *(const half8*)&khB[koff];
      nk1 = *(const half8*)&khB[koff + 8];
      const int vc = min(mbn + sg, KNTOK - 16);
      const size_t voff = (size_t)rr * KNTOK + vc;
      nv0 = *(const half8*)&vtB[voff];
      nv1 = *(const half8*)&vtB[voff + 8];
    }

    // ---- S = Q K^T (Q from registers) ----
    floatx4 sc[2][4];
#pragma unroll
    for (int i = 0; i < 2; ++i)
#pragma unroll
      for (int t = 0; t < 4; ++t) sc[i][t] = (floatx4){0.f, 0.f, 0.f, 0.f};
#pragma unroll
    for (int ks = 0; ks < 2; ++ks) {
      const int kk = ks * 32 + quad * 8;
#pragma unroll
      for (int t = 0; t < 4; ++t) {
        const half8 bk = *(const half8*)&Khs[t * 16 + tx][kk];
#pragma unroll
        for (int i = 0; i < 2; ++i)
          sc[i][t] = __builtin_amdgcn_mfma_f32_16x16x32_f16(qreg[i][ks], bk, sc[i][t], 0, 0, 0);
      }
    }

    // ---- static-max softmax ----
#pragma unroll
    for (int i = 0; i < 2; ++i)
#pragma unroll
      for (int rg = 0; rg < 4; ++rg) {
        const float4 bb = *(const float4*)&biasT[bbase[i][rg] + jc * 64];
        const float p0 = __expf(fmaf(sc[i][0][rg], SCALE_ATT, bb.x));
        const float p1 = __expf(fmaf(sc[i][1][rg], SCALE_ATT, bb.y));
        const float p2 = __expf(fmaf(sc[i][2][rg], SCALE_ATT, bb.z));
        const float p3 = __expf(fmaf(sc[i][3][rg], SCALE_ATT, bb.w));
        l_part[i][rg] += (p0 + p1) + (p2 + p3);
        const int prow = i * 16 + quad * 4 + rg;
        PsW[prow * LSTR + 0 * 16 + tx] = (f16)p0;
        PsW[prow * LSTR + 1 * 16 + tx] = (f16)p1;
        PsW[prow * LSTR + 2 * 16 + tx] = (f16)p2;
        PsW[prow * LSTR + 3 * 16 + tx] = (f16)p3;
      }

    // ---- O += P V ----
#pragma unroll
    for (int ks = 0; ks < 2; ++ks) {
      const int kk = ks * 32 + quad * 8;
      half8 ap[2];
#pragma unroll
      for (int i = 0; i < 2; ++i)
        ap[i] = *(const half8*)&PsW[(i * 16 + tx) * LSTR + kk];
#pragma unroll
      for (int t = 0; t < 4; ++t) {
        const half8 bv = *(const half8*)&Vts[t * 16 + tx][kk];
#pragma unroll
        for (int i = 0; i < 2; ++i)
          acc_o[i][t] = __builtin_amdgcn_mfma_f32_16x16x32_f16(ap[i], bv, acc_o[i][t], 0, 0, 0);
      }
    }
    __syncthreads();
    if (jc < 12) {
      *(half8*)&Khs[rr][sg]     = nk0;
      *(half8*)&Khs[rr][sg + 8] = nk1;
      *(half8*)&Vts[rr][sg]     = nv0;
      *(half8*)&Vts[rr][sg + 8] = nv1;
    }
    __syncthreads();
  }

  // ---- epilogue ----
#pragma unroll
  for (int i = 0; i < 2; ++i)
#pragma unroll
    for (int rg = 0; rg < 4; ++rg) {
      float l = l_part[i][rg];
#pragma unroll
      for (int msk = 1; msk < 16; msk <<= 1) l += __shfl_xor(l, msk, 64);
      const float inv = 1.f / l;
      const int grow = n0 + wv * 32 + i * 16 + quad * 4 + rg;
      if (grow < NTOK) {
        const size_t base = ((size_t)b * NTOK + grow) * CDIM + h * HD;
#pragma unroll
        for (int t = 0; t < 4; ++t)
          Oh[base + t * 16 + tx] = (f16)(acc_o[i][t][rg] * inv);
      }
    }
}

// ---------------------------------------------------------------------------
// Output projection (400 blocks, 128x128) + bp, fp32 transposed (b, co, n).
// ---------------------------------------------------------------------------
__global__ __launch_bounds__(256) void k_outproj(const f16* __restrict__ Og,
                                                 const f16* __restrict__ WpT,
                                                 const float* __restrict__ bp,
                                                 float* __restrict__ out) {
  __shared__ GemmSmem sm;
  GEMM128_PRE();
  const int bid = blockIdx.x;
  const int b = bid / 100, t = bid % 100;
  const int m0 = (t >> 2) * 128, n0 = (t & 3) * 128;
  const f16* ab = Og + (size_t)b * NTOK * CDIM;
  const int r0 = wv * 32 + lr, r1 = r0 + 16;
  const f16* a0 = ab + (size_t)min(m0 + r0, NTOK - 1) * CDIM + lc;
  const f16* a1 = ab + (size_t)min(m0 + r1, NTOK - 1) * CDIM + lc;
  const f16* b0 = WpT + (size_t)(n0 + r0) * CDIM + lc;
  const f16* b1 = WpT + (size_t)(n0 + r1) * CDIM + lc;
  gemm128(&sm, a0, a1, b0, b1, lane, wv, wm, wn, quad, tx, acc);
#pragma unroll
  for (int j = 0; j < 4; ++j) {
    const int co = n0 + wn * 64 + j * 16 + tx;
    const float bpv = bp[co];
    float* obase = out + ((size_t)b * CDIM + co) * NTOK;
#pragma unroll
    for (int i = 0; i < 4; ++i) {
      const int mb4 = m0 + wm * 64 + i * 16 + quad * 4;
      if (mb4 < NTOK) {
        floatx4 v = acc[i][j] + bpv;
        *(floatx4*)&obase[mb4] = v;
      }
    }
  }
}

// ---------------------------------------------------------------------------
extern "C" void kernel_launch(void* const* d_in, const int* in_sizes, int n_in,
                              void* d_out, int out_size, void* d_ws, size_t ws_size,
                              hipStream_t stream) {
  const float* x     = (const float*)d_in[0];
  const float* Wq    = (const float*)d_in[1];
  const float* Wkv   = (const float*)d_in[2];
  const float* Wsr   = (const float*)d_in[3];
  const float* b_sr  = (const float*)d_in[4];
  const float* gamma = (const float*)d_in[5];
  const float* beta  = (const float*)d_in[6];
  const float* Wp    = (const float*)d_in[7];
  const float* bp    = (const float*)d_in[8];
  const float* pos   = (const float*)d_in[9];
  float* out = (float*)d_out;

  char* p = (char*)d_ws;
  auto alloc = [&](size_t bytes) -> void* {
    void* r = (void*)p;
    p += (bytes + 255) & ~(size_t)255;
    return r;
  };
  const size_t SZ_BNC = (size_t)BATCH * NTOK * CDIM;
  const size_t SZ_BKC = (size_t)BATCH * KNTOK * CDIM;
  const size_t SZ_KV  = (size_t)BATCH * NHEAD * KNTOK * HD;

  f16* xT    = (f16*)alloc(SZ_BNC * 2);          // aliased later as Og
  f16* WqT   = (f16*)alloc(512 * 512 * 2);
  f16* WkvT  = (f16*)alloc(1024 * 512 * 2);
  f16* WpT   = (f16*)alloc(512 * 512 * 2);
  f16* WsrP  = (f16*)alloc(512 * 2048 * 2);
  f16* Qh    = (f16*)alloc(SZ_BNC * 2);
  float* XRp = (float*)alloc(SZ_BKC * 4 * 2);    // 2 split-K partials; aliased: Kh
  f16* XRh   = (f16*)alloc(SZ_BKC * 2);
  f16* Vt    = (f16*)alloc(SZ_KV * 2);
  float* biasT = (float*)alloc((size_t)NTOK * BIAS_LD * 4);

  f16* Kh = (f16*)XRp;  // XRp dead after k_ln; Kh written by k_kvproj
  f16* Og = xT;         // xT dead after k_gemmA

  const dim3 blk(256);
  k_prep   <<<dim3(5472), blk, 0, stream>>>(x, Wq, Wkv, Wp, Wsr, pos,
                                            xT, WqT, WkvT, WpT, WsrP, biasT);
  k_gemmA  <<<dim3(624),  blk, 0, stream>>>(xT, WqT, Qh, WsrP, XRp);
  k_ln     <<<dim3(BATCH * KNTOK), blk, 0, stream>>>(XRp, b_sr, gamma, beta, XRh);
  k_kvproj <<<dim3(224),  blk, 0, stream>>>(XRh, WkvT, Kh, Vt);
  k_attn   <<<dim3(BATCH * NHEAD, 25), blk, 0, stream>>>(Qh, Kh, Vt, biasT, Og);
  k_outproj<<<dim3(400),  blk, 0, stream>>>(Og, WpT, bp, out);
}

// Round 12
// 287.525 us; speedup vs baseline: 1.1392x; 1.1392x over previous
//
#include <hip/hip_runtime.h>
#include <hip/hip_bf16.h>
#include <cstdint>

constexpr int BATCH = 4;
constexpr int CDIM  = 512;
constexpr int NHEAD = 8;
constexpr int HD    = 64;
constexpr int FSP   = 56;
constexpr int NTOK  = FSP * FSP;  // 3136
constexpr int KH    = 28;
constexpr int KNTOK = KH * KH;    // 784
constexpr float SCALE_ATT = 0.125f;
constexpr int BIAS_LD = 832;      // 13 chunks * 64, tail baked to -3e4

typedef _Float16 f16;
typedef __attribute__((ext_vector_type(8))) _Float16 half8;
typedef __attribute__((ext_vector_type(4))) float  floatx4;

// ---------------------------------------------------------------------------
// 64x64 fp32->fp16 transpose helper (shared-arena version).
// ---------------------------------------------------------------------------
__device__ __forceinline__ void tr64(const float* __restrict__ in,
                                     f16* __restrict__ out, int R, int C,
                                     int r0, int c0, float (*sm)[65], int tid) {
  const int rr = tid >> 2, cs = (tid & 3) * 16;
  const float* src = in + (size_t)(r0 + rr) * C + c0 + cs;
#pragma unroll
  for (int j = 0; j < 16; j += 4) *(float4*)&sm[rr][cs + j] = *(const float4*)&src[j];
  __syncthreads();
  f16* dh = out + (size_t)(c0 + rr) * R + r0 + cs;
  half8 v0, v1;
#pragma unroll
  for (int j = 0; j < 8; ++j) v0[j] = (f16)sm[cs + j][rr];
#pragma unroll
  for (int j = 0; j < 8; ++j) v1[j] = (f16)sm[cs + 8 + j][rr];
  *(half8*)&dh[0] = v0;
  *(half8*)&dh[8] = v1;
}

// ---------------------------------------------------------------------------
// Prep-1: only what k_gemmA needs — xT (1568), WqT (64), WsrP (512).
// ---------------------------------------------------------------------------
__global__ __launch_bounds__(256) void k_prep(const float* __restrict__ x,
                                              const float* __restrict__ Wq,
                                              const float* __restrict__ Wsr,
                                              f16* __restrict__ xT,
                                              f16* __restrict__ WqT,
                                              f16* __restrict__ WsrP) {
  __shared__ float sm[64][65];
  const int tid = threadIdx.x;
  int bid = blockIdx.x;
  if (bid < 1568) {
    const int b = bid / 392, r = bid % 392;
    tr64(x + (size_t)b * CDIM * NTOK, xT + (size_t)b * NTOK * CDIM,
         CDIM, NTOK, (r % 8) * 64, (r / 8) * 64, sm, tid);
    return;
  }
  bid -= 1568;
  if (bid < 64) { tr64(Wq, WqT, 512, 512, (bid % 8) * 64, (bid / 8) * 64, sm, tid); return; }
  bid -= 64;
  {
    const float* src = Wsr + (size_t)bid * 2048;
    f16* dh = WsrP + (size_t)bid * 2048;
    for (int kp = tid; kp < 2048; kp += 256) {
      const int dd = kp >> 9, c = kp & 511;
      dh[kp] = (f16)src[c * 4 + dd];
    }
  }
}

// ---------------------------------------------------------------------------
// m97-style MFMA GEMM core: 128x128 tile, BK=32, unpadded LDS [128][32],
// async global->LDS staging via global_load_lds width-16.
// ---------------------------------------------------------------------------
struct GemmSmem { f16 A[128 * 32]; f16 B[128 * 32]; };  // 8 KB + 8 KB

__device__ __forceinline__ void gl_lds(const f16* g, f16* l) {
  __builtin_amdgcn_global_load_lds(
      (const __attribute__((address_space(1))) void*)g,
      (__attribute__((address_space(3))) void*)l, 16, 0, 0);
}

__device__ __forceinline__ void gemm128(GemmSmem* sm,
    const f16* a0, const f16* a1, const f16* b0, const f16* b1,
    int lane, int wv, int wm, int wn, int quad, int tx,
    floatx4 acc[4][4]) {
  f16* lA0 = sm->A + wv * 1024 + lane * 8;
  f16* lA1 = sm->A + wv * 1024 + 512 + lane * 8;
  f16* lB0 = sm->B + wv * 1024 + lane * 8;
  f16* lB1 = sm->B + wv * 1024 + 512 + lane * 8;
  for (int it = 0; it < 16; ++it) {
    gl_lds(a0 + it * 32, lA0);
    gl_lds(a1 + it * 32, lA1);
    gl_lds(b0 + it * 32, lB0);
    gl_lds(b1 + it * 32, lB1);
    __syncthreads();
    half8 af[4], bf[4];
#pragma unroll
    for (int i = 0; i < 4; ++i)
      af[i] = *(const half8*)&sm->A[(wm * 64 + i * 16 + tx) * 32 + quad * 8];
#pragma unroll
    for (int j = 0; j < 4; ++j)
      bf[j] = *(const half8*)&sm->B[(wn * 64 + j * 16 + tx) * 32 + quad * 8];
#pragma unroll
    for (int j = 0; j < 4; ++j)
#pragma unroll
      for (int i = 0; i < 4; ++i)
        acc[i][j] = __builtin_amdgcn_mfma_f32_16x16x32_f16(af[i], bf[j], acc[i][j], 0, 0, 0);
    __syncthreads();
  }
}

#define GEMM128_VARS()                                                    \
  const int lane = tid & 63, wv = tid >> 6;                               \
  const int wm = wv & 1, wn = wv >> 1, quad = lane >> 4, tx = lane & 15;  \
  const int lr = lane >> 2, lc = (lane & 3) * 8;                          \
  floatx4 acc[4][4];                                                      \
  _Pragma("unroll") for (int i = 0; i < 4; ++i)                           \
  _Pragma("unroll") for (int j = 0; j < 4; ++j)                           \
      acc[i][j] = (floatx4){0.f, 0.f, 0.f, 0.f};

// ---------------------------------------------------------------------------
// GEMM-A + tail filler.  Heavy blocks first:
//   [0,400)       Q projection  (b4 x m25 x n4, 128x128)
//   [400,848)     SR-conv split-K=4  ((b,kc)16 x m7 x n4)
// Light filler blocks (independent work, consumed by later kernels):
//   [848,976)     WkvT transpose (128)
//   [976,1040)    WpT transpose (64)
//   [1040,4176)   biasT build (3136; analytic rel idx, coalesced pos reads)
// ---------------------------------------------------------------------------
__global__ __launch_bounds__(256) void k_gemmA(const f16* __restrict__ xT,
                                               const f16* __restrict__ WqT,
                                               f16* __restrict__ Qh,
                                               const f16* __restrict__ WsrP,
                                               float* __restrict__ XRp,
                                               const float* __restrict__ Wkv,
                                               const float* __restrict__ Wp,
                                               const float* __restrict__ pos,
                                               f16* __restrict__ WkvT,
                                               f16* __restrict__ WpT,
                                               float* __restrict__ biasT) {
  __shared__ __align__(16) char arena[64 * 65 * 4];
  GemmSmem* sm = (GemmSmem*)arena;
  float (*tsm)[65] = (float(*)[65])arena;
  const int tid = threadIdx.x;
  int bid = blockIdx.x;
  if (bid < 848) {
    GEMM128_VARS();
    if (bid < 400) {          // ---- Q projection ----
      const int b = bid / 100, t = bid % 100;
      const int m0 = (t >> 2) * 128, n0 = (t & 3) * 128;
      const f16* xb = xT + (size_t)b * NTOK * CDIM;
      const int r0 = wv * 32 + lr, r1 = r0 + 16;
      const f16* a0 = xb + (size_t)min(m0 + r0, NTOK - 1) * CDIM + lc;
      const f16* a1 = xb + (size_t)min(m0 + r1, NTOK - 1) * CDIM + lc;
      const f16* b0 = WqT + (size_t)(n0 + r0) * CDIM + lc;
      const f16* b1 = WqT + (size_t)(n0 + r1) * CDIM + lc;
      gemm128(sm, a0, a1, b0, b1, lane, wv, wm, wn, quad, tx, acc);
      f16* qhB = Qh + (size_t)b * NTOK * CDIM;
#pragma unroll
      for (int i = 0; i < 4; ++i)
#pragma unroll
        for (int rg = 0; rg < 4; ++rg) {
          const int m = m0 + wm * 64 + i * 16 + quad * 4 + rg;
          if (m >= NTOK) continue;
#pragma unroll
          for (int j = 0; j < 4; ++j)
            qhB[(size_t)m * CDIM + n0 + wn * 64 + j * 16 + tx] = (f16)acc[i][j][rg];
        }
    } else {                  // ---- SR conv split-K=4 ----
      bid -= 400;
      const int bkc = bid / 28, r = bid % 28;
      const int b = bkc >> 2, kc = bkc & 3;
      const int m0 = (r >> 2) * 128, n0 = (r & 3) * 128;
      const f16* xb = xT + (size_t)b * NTOK * CDIM;
      const int r0 = wv * 32 + lr, r1 = r0 + 16;
      int am0 = m0 + r0; if (am0 >= KNTOK) am0 = 0;
      int am1 = m0 + r1; if (am1 >= KNTOK) am1 = 0;
      const int sp0 = 112 * (am0 / KH) + 2 * (am0 % KH) + (kc >> 1) * FSP + (kc & 1);
      const int sp1 = 112 * (am1 / KH) + 2 * (am1 % KH) + (kc >> 1) * FSP + (kc & 1);
      const f16* a0 = xb + (size_t)sp0 * CDIM + lc;
      const f16* a1 = xb + (size_t)sp1 * CDIM + lc;
      const f16* b0 = WsrP + (size_t)(n0 + r0) * 2048 + kc * 512 + lc;
      const f16* b1 = WsrP + (size_t)(n0 + r1) * 2048 + kc * 512 + lc;
      gemm128(sm, a0, a1, b0, b1, lane, wv, wm, wn, quad, tx, acc);
      float* dst = XRp + (size_t)(kc * BATCH + b) * KNTOK * CDIM;
#pragma unroll
      for (int i = 0; i < 4; ++i)
#pragma unroll
        for (int rg = 0; rg < 4; ++rg) {
          const int m = m0 + wm * 64 + i * 16 + quad * 4 + rg;
          if (m >= KNTOK) continue;
#pragma unroll
          for (int j = 0; j < 4; ++j)
            dst[(size_t)m * CDIM + n0 + wn * 64 + j * 16 + tx] = acc[i][j][rg];
        }
    }
    return;
  }
  bid -= 848;
  if (bid < 128) { tr64(Wkv, WkvT, 512, 1024, (bid % 8) * 64, (bid / 8) * 64, tsm, tid); return; }
  bid -= 128;
  if (bid < 64)  { tr64(Wp,  WpT,  512, 512,  (bid % 8) * 64, (bid / 8) * 64, tsm, tid); return; }
  bid -= 64;
  {  // ---- biasT build ----
    const int n = bid;
    const int in_ = n / FSP, jn = n % FSP;
    const int cbase = 55 * 111 + 55 - in_ * 111 - jn;
    float* dst = biasT + (size_t)n * BIAS_LD;
    for (int m = tid; m < BIAS_LD; m += 256) {   // coalesced pos reads
      float v = -30000.f;
      if (m < KNTOK) v = pos[cbase + (m / FSP) * 111 + (m % FSP)];
      const int jc = m >> 6, w = m & 63, t = w >> 4, txx = w & 15;
      dst[jc * 64 + txx * 4 + t] = v;
    }
  }
}

// ---------------------------------------------------------------------------
// LN: sum 4 split-K partials + b_sr, LayerNorm, output fp16.  (R9)
// ---------------------------------------------------------------------------
__global__ __launch_bounds__(256) void k_ln(const float* __restrict__ XRp,
                                            const float* __restrict__ b_sr,
                                            const float* __restrict__ gamma,
                                            const float* __restrict__ beta,
                                            f16* __restrict__ oh) {
  const int row = blockIdx.x;
  const size_t slab = (size_t)BATCH * KNTOK * CDIM;
  const float* p = XRp + (size_t)row * CDIM;
  const int tid = threadIdx.x;
  const float v0 = p[tid] + p[tid + slab] + p[tid + 2 * slab] + p[tid + 3 * slab]
                 + b_sr[tid];
  const float v1 = p[tid + 256] + p[tid + 256 + slab] + p[tid + 256 + 2 * slab]
                 + p[tid + 256 + 3 * slab] + b_sr[tid + 256];
  float s = v0 + v1;
  float s2 = v0 * v0 + v1 * v1;
#pragma unroll
  for (int mask = 32; mask >= 1; mask >>= 1) {
    s  += __shfl_xor(s, mask, 64);
    s2 += __shfl_xor(s2, mask, 64);
  }
  __shared__ float ws[4], ws2[4];
  const int wid = tid >> 6;
  if ((tid & 63) == 0) { ws[wid] = s; ws2[wid] = s2; }
  __syncthreads();
  const float ts  = ws[0] + ws[1] + ws[2] + ws[3];
  const float ts2 = ws2[0] + ws2[1] + ws2[2] + ws2[3];
  const float mu  = ts * (1.f / CDIM);
  const float var = ts2 * (1.f / CDIM) - mu * mu;
  const float rs  = rsqrtf(var + 1e-5f);
  const size_t base = (size_t)row * CDIM;
  oh[base + tid]       = (f16)((v0 - mu) * rs * gamma[tid] + beta[tid]);
  oh[base + tid + 256] = (f16)((v1 - mu) * rs * gamma[tid + 256] + beta[tid + 256]);
}

// ---------------------------------------------------------------------------
// KV projection (224 blocks) + scatter.  K -> [b][h][m][d]; V -> [b][h][d][m].
// ---------------------------------------------------------------------------
__global__ __launch_bounds__(256) void k_kvproj(const f16* __restrict__ XRh,
                                                const f16* __restrict__ WkvT,
                                                f16* __restrict__ Kh,
                                                f16* __restrict__ Vt) {
  __shared__ GemmSmem smem;
  GemmSmem* sm = &smem;
  const int tid = threadIdx.x;
  GEMM128_VARS();
  const int bid = blockIdx.x;
  const int b = bid / 56, r = bid % 56;
  const int m0 = (r / 8) * 128, n0 = (r % 8) * 128;
  const f16* ab = XRh + (size_t)b * KNTOK * CDIM;
  const int r0 = wv * 32 + lr, r1 = r0 + 16;
  const f16* a0 = ab + (size_t)min(m0 + r0, KNTOK - 1) * CDIM + lc;
  const f16* a1 = ab + (size_t)min(m0 + r1, KNTOK - 1) * CDIM + lc;
  const f16* b0 = WkvT + (size_t)(n0 + r0) * CDIM + lc;
  const f16* b1 = WkvT + (size_t)(n0 + r1) * CDIM + lc;
  gemm128(sm, a0, a1, b0, b1, lane, wv, wm, wn, quad, tx, acc);
#pragma unroll
  for (int i = 0; i < 4; ++i)
#pragma unroll
    for (int rg = 0; rg < 4; ++rg) {
      const int m = m0 + wm * 64 + i * 16 + quad * 4 + rg;
      if (m >= KNTOK) continue;
#pragma unroll
      for (int j = 0; j < 4; ++j) {
        const int o2 = n0 + wn * 64 + j * 16 + tx;
        const int d = o2 >> 4, hh = (o2 >> 1) & 7;
        const float v = acc[i][j][rg];
        if (o2 & 1)
          Vt[((size_t)(b * NHEAD + hh) * HD + d) * KNTOK + m] = (f16)v;
        else
          Kh[((size_t)(b * NHEAD + hh) * KNTOK + m) * HD + d] = (f16)v;
      }
    }
}

// ---------------------------------------------------------------------------
// Attention (R9, verbatim): 128-row Q tiles, Q staged in LDS, LDS-staged K/V
// chunks with register prefetch, static-max softmax.
// Grid (32 = b*8+h fast, 25 q-tiles).  LDS 55.3 KB -> 2 blocks/CU.
// ---------------------------------------------------------------------------
#define LSTR 72
__global__ __launch_bounds__(256) void k_attn(const f16* __restrict__ Qh,
                                              const f16* __restrict__ Kh,
                                              const f16* __restrict__ Vt,
                                              const float* __restrict__ biasT,
                                              f16* __restrict__ Oh) {
  __shared__ f16 Qhs[128][LSTR], Khs[64][LSTR], Vts[64][LSTR];
  __shared__ f16 Ps[4][32][LSTR];
  const int b = blockIdx.x >> 3, h = blockIdx.x & 7;
  const int n0 = blockIdx.y * 128;
  const int tid = threadIdx.x, lane = tid & 63, wv = tid >> 6;
  const int quad = lane >> 4, tx = lane & 15;
  const int rr = tid >> 2, sg = (tid & 3) * 16;   // K/V staging coords
  const int qr = tid >> 1, qs = (tid & 1) * 32;   // Q staging coords

  const f16* khB = Kh + (size_t)(b * NHEAD + h) * KNTOK * HD;
  const f16* vtB = Vt + (size_t)(b * NHEAD + h) * HD * KNTOK;

  {  // stage Q (128 rows x 64, clamp tail rows) and chunk 0 of K/V
    const int qrow = min(n0 + qr, NTOK - 1);
    const f16* src = Qh + ((size_t)b * NTOK + qrow) * CDIM + h * HD + qs;
    *(half8*)&Qhs[qr][qs]      = *(const half8*)&src[0];
    *(half8*)&Qhs[qr][qs + 8]  = *(const half8*)&src[8];
    *(half8*)&Qhs[qr][qs + 16] = *(const half8*)&src[16];
    *(half8*)&Qhs[qr][qs + 24] = *(const half8*)&src[24];
    const size_t koff = (size_t)rr * HD + sg;
    *(half8*)&Khs[rr][sg]     = *(const half8*)&khB[koff];
    *(half8*)&Khs[rr][sg + 8] = *(const half8*)&khB[koff + 8];
    const size_t voff = (size_t)rr * KNTOK + sg;
    *(half8*)&Vts[rr][sg]     = *(const half8*)&vtB[voff];
    *(half8*)&Vts[rr][sg + 8] = *(const half8*)&vtB[voff + 8];
  }

  size_t bbase[2][4];
#pragma unroll
  for (int i = 0; i < 2; ++i)
#pragma unroll
    for (int rg = 0; rg < 4; ++rg) {
      const int grow = min(n0 + wv * 32 + i * 16 + quad * 4 + rg, NTOK - 1);
      bbase[i][rg] = (size_t)grow * BIAS_LD + tx * 4;
    }

  floatx4 acc_o[2][4];
#pragma unroll
  for (int i = 0; i < 2; ++i)
#pragma unroll
    for (int t = 0; t < 4; ++t) acc_o[i][t] = (floatx4){0.f, 0.f, 0.f, 0.f};
  float l_part[2][4] = {};
  __syncthreads();

  half8 nk0, nk1, nv0, nv1;
  for (int jc = 0; jc < 13; ++jc) {
    if (jc < 12) {  // register prefetch of next K/V chunk
      const int mbn = (jc + 1) * 64;
      const int km = min(mbn + rr, KNTOK - 1);
      const size_t koff = (size_t)km * HD + sg;
      nk0 = *(const half8*)&khB[koff];
      nk1 = *(const half8*)&khB[koff + 8];
      const int vc = min(mbn + sg, KNTOK - 16);
      const size_t voff = (size_t)rr * KNTOK + vc;
      nv0 = *(const half8*)&vtB[voff];
      nv1 = *(const half8*)&vtB[voff + 8];
    }

    // ---- S = Q K^T ----
    floatx4 sc[2][4];
#pragma unroll
    for (int i = 0; i < 2; ++i)
#pragma unroll
      for (int t = 0; t < 4; ++t) sc[i][t] = (floatx4){0.f, 0.f, 0.f, 0.f};
#pragma unroll
    for (int ks = 0; ks < 2; ++ks) {
      const int kk = ks * 32 + quad * 8;
      half8 aq[2];
#pragma unroll
      for (int i = 0; i < 2; ++i)
        aq[i] = *(const half8*)&Qhs[wv * 32 + i * 16 + tx][kk];
#pragma unroll
      for (int t = 0; t < 4; ++t) {
        const half8 bk = *(const half8*)&Khs[t * 16 + tx][kk];
#pragma unroll
        for (int i = 0; i < 2; ++i)
          sc[i][t] = __builtin_amdgcn_mfma_f32_16x16x32_f16(aq[i], bk, sc[i][t], 0, 0, 0);
      }
    }

    // ---- static-max softmax ----
#pragma unroll
    for (int i = 0; i < 2; ++i)
#pragma unroll
      for (int rg = 0; rg < 4; ++rg) {
        const float4 bb = *(const float4*)&biasT[bbase[i][rg] + jc * 64];
        const float p0 = __expf(fmaf(sc[i][0][rg], SCALE_ATT, bb.x));
        const float p1 = __expf(fmaf(sc[i][1][rg], SCALE_ATT, bb.y));
        const float p2 = __expf(fmaf(sc[i][2][rg], SCALE_ATT, bb.z));
        const float p3 = __expf(fmaf(sc[i][3][rg], SCALE_ATT, bb.w));
        l_part[i][rg] += (p0 + p1) + (p2 + p3);
        const int prow = i * 16 + quad * 4 + rg;
        Ps[wv][prow][0 * 16 + tx] = (f16)p0;
        Ps[wv][prow][1 * 16 + tx] = (f16)p1;
        Ps[wv][prow][2 * 16 + tx] = (f16)p2;
        Ps[wv][prow][3 * 16 + tx] = (f16)p3;
      }

    // ---- O += P V ----
#pragma unroll
    for (int ks = 0; ks < 2; ++ks) {
      const int kk = ks * 32 + quad * 8;
      half8 ap[2];
#pragma unroll
      for (int i = 0; i < 2; ++i)
        ap[i] = *(const half8*)&Ps[wv][i * 16 + tx][kk];
#pragma unroll
      for (int t = 0; t < 4; ++t) {
        const half8 bv = *(const half8*)&Vts[t * 16 + tx][kk];
#pragma unroll
        for (int i = 0; i < 2; ++i)
          acc_o[i][t] = __builtin_amdgcn_mfma_f32_16x16x32_f16(ap[i], bv, acc_o[i][t], 0, 0, 0);
      }
    }
    __syncthreads();
    if (jc < 12) {
      *(half8*)&Khs[rr][sg]     = nk0;
      *(half8*)&Khs[rr][sg + 8] = nk1;
      *(half8*)&Vts[rr][sg]     = nv0;
      *(half8*)&Vts[rr][sg + 8] = nv1;
    }
    __syncthreads();
  }

  // ---- epilogue ----
#pragma unroll
  for (int i = 0; i < 2; ++i)
#pragma unroll
    for (int rg = 0; rg < 4; ++rg) {
      float l = l_part[i][rg];
#pragma unroll
      for (int msk = 1; msk < 16; msk <<= 1) l += __shfl_xor(l, msk, 64);
      const float inv = 1.f / l;
      const int grow = n0 + wv * 32 + i * 16 + quad * 4 + rg;
      if (grow < NTOK) {
        const size_t base = ((size_t)b * NTOK + grow) * CDIM + h * HD;
#pragma unroll
        for (int t = 0; t < 4; ++t)
          Oh[base + t * 16 + tx] = (f16)(acc_o[i][t][rg] * inv);
      }
    }
}

// ---------------------------------------------------------------------------
// Output projection (400 blocks, 128x128) + bp, fp32 transposed (b, co, n).
// ---------------------------------------------------------------------------
__global__ __launch_bounds__(256) void k_outproj(const f16* __restrict__ Og,
                                                 const f16* __restrict__ WpT,
                                                 const float* __restrict__ bp,
                                                 float* __restrict__ out) {
  __shared__ GemmSmem smem;
  GemmSmem* sm = &smem;
  const int tid = threadIdx.x;
  GEMM128_VARS();
  const int bid = blockIdx.x;
  const int b = bid / 100, t = bid % 100;
  const int m0 = (t >> 2) * 128, n0 = (t & 3) * 128;
  const f16* ab = Og + (size_t)b * NTOK * CDIM;
  const int r0 = wv * 32 + lr, r1 = r0 + 16;
  const f16* a0 = ab + (size_t)min(m0 + r0, NTOK - 1) * CDIM + lc;
  const f16* a1 = ab + (size_t)min(m0 + r1, NTOK - 1) * CDIM + lc;
  const f16* b0 = WpT + (size_t)(n0 + r0) * CDIM + lc;
  const f16* b1 = WpT + (size_t)(n0 + r1) * CDIM + lc;
  gemm128(sm, a0, a1, b0, b1, lane, wv, wm, wn, quad, tx, acc);
#pragma unroll
  for (int j = 0; j < 4; ++j) {
    const int co = n0 + wn * 64 + j * 16 + tx;
    const float bpv = bp[co];
    float* obase = out + ((size_t)b * CDIM + co) * NTOK;
#pragma unroll
    for (int i = 0; i < 4; ++i) {
      const int mb4 = m0 + wm * 64 + i * 16 + quad * 4;
      if (mb4 < NTOK) {
        floatx4 v = acc[i][j] + bpv;
        *(floatx4*)&obase[mb4] = v;
      }
    }
  }
}

// ---------------------------------------------------------------------------
extern "C" void kernel_launch(void* const* d_in, const int* in_sizes, int n_in,
                              void* d_out, int out_size, void* d_ws, size_t ws_size,
                              hipStream_t stream) {
  const float* x     = (const float*)d_in[0];
  const float* Wq    = (const float*)d_in[1];
  const float* Wkv   = (const float*)d_in[2];
  const float* Wsr   = (const float*)d_in[3];
  const float* b_sr  = (const float*)d_in[4];
  const float* gamma = (const float*)d_in[5];
  const float* beta  = (const float*)d_in[6];
  const float* Wp    = (const float*)d_in[7];
  const float* bp    = (const float*)d_in[8];
  const float* pos   = (const float*)d_in[9];
  float* out = (float*)d_out;

  char* p = (char*)d_ws;
  auto alloc = [&](size_t bytes) -> void* {
    void* r = (void*)p;
    p += (bytes + 255) & ~(size_t)255;
    return r;
  };
  const size_t SZ_BNC = (size_t)BATCH * NTOK * CDIM;
  const size_t SZ_BKC = (size_t)BATCH * KNTOK * CDIM;
  const size_t SZ_KV  = (size_t)BATCH * NHEAD * KNTOK * HD;

  f16* xT    = (f16*)alloc(SZ_BNC * 2);          // aliased later as Og
  f16* WqT   = (f16*)alloc(512 * 512 * 2);
  f16* WkvT  = (f16*)alloc(1024 * 512 * 2);
  f16* WpT   = (f16*)alloc(512 * 512 * 2);
  f16* WsrP  = (f16*)alloc(512 * 2048 * 2);
  f16* Qh    = (f16*)alloc(SZ_BNC * 2);
  float* XRp = (float*)alloc(SZ_BKC * 4 * 4);    // 4 split-K partials; aliased: Kh
  f16* XRh   = (f16*)alloc(SZ_BKC * 2);
  f16* Vt    = (f16*)alloc(SZ_KV * 2);
  float* biasT = (float*)alloc((size_t)NTOK * BIAS_LD * 4);

  f16* Kh = (f16*)XRp;  // XRp dead after k_ln; Kh written by k_kvproj
  f16* Og = xT;         // xT dead after k_gemmA

  const dim3 blk(256);
  k_prep   <<<dim3(2144), blk, 0, stream>>>(x, Wq, Wsr, xT, WqT, WsrP);
  k_gemmA  <<<dim3(4176), blk, 0, stream>>>(xT, WqT, Qh, WsrP, XRp,
                                            Wkv, Wp, pos, WkvT, WpT, biasT);
  k_ln     <<<dim3(BATCH * KNTOK), blk, 0, stream>>>(XRp, b_sr, gamma, beta, XRh);
  k_kvproj <<<dim3(224),  blk, 0, stream>>>(XRh, WkvT, Kh, Vt);
  k_attn   <<<dim3(BATCH * NHEAD, 25), blk, 0, stream>>>(Qh, Kh, Vt, biasT, Og);
  k_outproj<<<dim3(400),  blk, 0, stream>>>(Og, WpT, bp, out);
}